// Round 6
// baseline (119.003 us; speedup 1.0000x reference)
//
#include <hip/hip_runtime.h>
#include <hip/hip_bf16.h>
#include <stdint.h>

#define NROWS 8192
#define NDIM  512
#define MARGIN 0.3f
#define NRB   128              // 64-row bands
#define NT    8256             // 128*129/2 upper-triangular 64x64 tiles

typedef __attribute__((ext_vector_type(16))) float floatx16;
typedef __attribute__((ext_vector_type(8)))  int   intx8;

// pack 4 floats -> 4 OCP e4m3 bytes (HW cvt, RNE, saturating)
__device__ inline unsigned cvt4_fp8(float4 f) {
  int v = 0;
  v = __builtin_amdgcn_cvt_pk_fp8_f32(f.x, f.y, v, false);
  v = __builtin_amdgcn_cvt_pk_fp8_f32(f.z, f.w, v, true);
  return (unsigned)v;
}

// fp32 -> fp8 e4m3, fully coalesced: lane i reads float4 i, writes u32 i
__global__ void convert_kernel(const float4* __restrict__ in, unsigned* __restrict__ out) {
  int i = blockIdx.x * blockDim.x + threadIdx.x;
  out[i] = cvt4_fp8(in[i]);
}

__device__ inline void gload_lds16(const void* g, void* l) {
  __builtin_amdgcn_global_load_lds(
      (const __attribute__((address_space(1))) unsigned int*)g,
      (__attribute__((address_space(3))) unsigned int*)l, 16, 0, 0);
}

// R21: ONE WAVE PER BLOCK, 64x64 tiles, ZERO barriers.
// R5 post-mortem: acc[2][4] = 128 AGPR + 128 VGPR on the unified gfx950 file
// -> 2 waves/SIMD -> one 8-wave block/CU resident (Occupancy 14%), and the
// per-block barrier lockstep exposed full DMA latency every K-phase (~6k cyc).
// Fix: single-wave blocks stage their OWN 64x64 tile pair (8 x 1KB
// global_load_lds per BK=64 stage) and are the sole consumer -> no s_barrier
// at all; s_waitcnt vmcnt orders DMA->ds_read within the wave (m03). Regs
// ~148/wave -> 12 waves/CU; LDS 2-stage x 16 KB -> 10 independent pipelines
// per CU: stalls in one wave no longer idle the CU (TLP replaces lockstep).
// Pipeline: distance-1; iter kt issues STAGE(kt+1), waits vmcnt(8) (stage kt
// landed, kt+1's 8 loads in flight), ds_read frags, 8 MFMA. WAR safe within
// the wave (reads of buf[kt-1] retired before it is restaged).
__launch_bounds__(64, 1)
__global__ void loss_kernel(const unsigned char* __restrict__ Xb, const int* __restrict__ tg,
                            float* __restrict__ partials) {
  __shared__ __align__(16) unsigned char As[2][4096];   // 64 rows x 64 B
  __shared__ __align__(16) unsigned char Bs[2][4096];

  // row-major upper-tri decode: consecutive blocks share bi (A-band locality)
  int t = blockIdx.x, bi = 0;
  while (t >= NRB - bi) { t -= NRB - bi; bi++; }
  const int bj = bi + t;

  const int lane = threadIdx.x & 63;
  const int g    = lane >> 5;            // MFMA k-group (0/1)
  const int m32  = lane & 31;            // MFMA row/col within 32

  const int rowBase = bi * 64;
  const int colBase = bj * 64;

  // staging: tile = 64 rows x 64 B = 4 chunks of 1 KB (16 rows each).
  // Chunk lane d: row = ch*16 + (d>>2), u_phys = d&3; fetches global k-unit
  // u_log = u_phys ^ ((srow>>2)&3)  (chunk-independent since ch*16>>2 is
  // 0 mod 4; conflict-free b128 reads, R14-verified swizzle).
  const int srow = lane >> 2;
  const int sup  = lane & 3;
  const int ul   = sup ^ ((srow >> 2) & 3);
  unsigned offA[4], offB[4];
#pragma unroll
  for (int ch = 0; ch < 4; ch++) {
    int row = ch * 16 + srow;
    offA[ch] = (unsigned)((rowBase + row) * NDIM + ul * 16);
    offB[ch] = (unsigned)((colBase + row) * NDIM + ul * 16);
  }

#define STAGE(KT, BUF)                                                    \
  do {                                                                    \
    _Pragma("unroll")                                                     \
    for (int ch = 0; ch < 4; ch++) {                                      \
      gload_lds16(Xb + offA[ch] + (KT) * 64, &As[BUF][ch * 1024]);        \
      gload_lds16(Xb + offB[ch] + (KT) * 64, &Bs[BUF][ch * 1024]);        \
    }                                                                     \
  } while (0)

  floatx16 acc[2][2];
#pragma unroll
  for (int a = 0; a < 2; a++)
#pragma unroll
    for (int b = 0; b < 2; b++) acc[a][b] = (floatx16)(0.f);

  STAGE(0, 0);                                         // 8 loads in flight

#pragma unroll
  for (int kt = 0; kt < 8; kt++) {
    const int buf = kt & 1;
    if (kt < 7) {
      STAGE(kt + 1, (kt + 1) & 1);                     // +8 -> 16 in flight
      asm volatile("s_waitcnt vmcnt(8)" ::: "memory"); // stage kt landed
    } else {
      asm volatile("s_waitcnt vmcnt(0)" ::: "memory");
    }

    // fragments: lane holds k = g*32 + [0,32) of its row as 2 x b128
    // (u_log = 2g, 2g+1), un-swizzled via u_phys = u_log ^ ((row>>2)&3)
    intx8 af[2], bf[2];
#pragma unroll
    for (int mt = 0; mt < 2; mt++) {
      const int row = mt * 32 + m32;
      const int x = (row >> 2) & 3;
      int4 lo = *(const int4*)(&As[buf][row * 64 + ((2 * g)     ^ x) * 16]);
      int4 hi = *(const int4*)(&As[buf][row * 64 + ((2 * g + 1) ^ x) * 16]);
      intx8 f; f[0]=lo.x; f[1]=lo.y; f[2]=lo.z; f[3]=lo.w;
               f[4]=hi.x; f[5]=hi.y; f[6]=hi.z; f[7]=hi.w;
      af[mt] = f;
    }
#pragma unroll
    for (int nt = 0; nt < 2; nt++) {
      const int row = nt * 32 + m32;
      const int x = (row >> 2) & 3;
      int4 lo = *(const int4*)(&Bs[buf][row * 64 + ((2 * g)     ^ x) * 16]);
      int4 hi = *(const int4*)(&Bs[buf][row * 64 + ((2 * g + 1) ^ x) * 16]);
      intx8 f; f[0]=lo.x; f[1]=lo.y; f[2]=lo.z; f[3]=lo.w;
               f[4]=hi.x; f[5]=hi.y; f[6]=hi.z; f[7]=hi.w;
      bf[nt] = f;
    }
#pragma unroll
    for (int mt = 0; mt < 2; mt++)
#pragma unroll
      for (int nt = 0; nt < 2; nt++)
        acc[mt][nt] = __builtin_amdgcn_mfma_scale_f32_32x32x64_f8f6f4(
            af[mt], bf[nt], acc[mt][nt],
            0 /*A fmt: fp8 e4m3*/, 0 /*B fmt: fp8 e4m3*/,
            0, 127 /*scaleA = 2^0*/, 0, 127 /*scaleB = 2^0*/);
  }

  // Epilogue (R0-verified logic, 64x64). 32x32 C/D layout [m74/m101]:
  // col = lane&31, row = (reg&3) + 8*(reg>>2) + 4*(lane>>5), reg in [0,16).
  float lsum = 0.f;
  const bool diag = (bi == bj);
  if (!diag) {
#pragma unroll
    for (int mt = 0; mt < 2; mt++) {
#pragma unroll
      for (int nt = 0; nt < 2; nt++) {
        const int tc = tg[colBase + nt * 32 + m32];
#pragma unroll
        for (int q = 0; q < 4; q++) {
          const int4 rlv = *(const int4*)(tg + rowBase + mt * 32 + 4 * g + 8 * q);
          const int rlab[4] = {rlv.x, rlv.y, rlv.z, rlv.w};
#pragma unroll
          for (int j = 0; j < 4; j++) {
            const float s = acc[mt][nt][q * 4 + j];
            lsum += (rlab[j] == tc) ? ((s < 1.f) ? 1.f - s : 0.f)
                                    : ((s > MARGIN) ? s : 0.f);
          }
        }
      }
    }
    lsum *= 2.f;     // pair weight hoisted
  } else {
#pragma unroll
    for (int mt = 0; mt < 2; mt++) {
#pragma unroll
      for (int nt = 0; nt < 2; nt++) {
        const int cloc = nt * 32 + m32;
        const int tc = tg[colBase + cloc];
        const int col = colBase + cloc;
#pragma unroll
        for (int q = 0; q < 4; q++) {
          const int rbase = mt * 32 + 4 * g + 8 * q;
          const int4 rlv = *(const int4*)(tg + rowBase + rbase);
          const int rlab[4] = {rlv.x, rlv.y, rlv.z, rlv.w};
#pragma unroll
          for (int j = 0; j < 4; j++) {
            const float s = acc[mt][nt][q * 4 + j];
            float c = (rlab[j] == tc) ? ((s < 1.f) ? 1.f - s : 0.f)
                                      : ((s > MARGIN) ? s : 0.f);
            const int row = rowBase + rbase + j;
            float wgt = (row < col) ? 2.f : ((row == col) ? 1.f : 0.f);
            lsum += wgt * c;
          }
        }
      }
    }
  }

  // single-wave reduce, one partial store, no __syncthreads anywhere
#pragma unroll
  for (int off = 32; off > 0; off >>= 1) lsum += __shfl_down(lsum, off, 64);
  if (lane == 0) partials[blockIdx.x] = lsum;
#undef STAGE
}

// NT partials -> scalar; one 1024-thread block (16 waves, ~8 iters each)
__global__ void reduce_kernel(const float* __restrict__ partials, float* __restrict__ out) {
  __shared__ float red[16];
  float s = 0.f;
  for (int i = threadIdx.x; i < NT; i += 1024) s += partials[i];
#pragma unroll
  for (int off = 32; off > 0; off >>= 1) s += __shfl_down(s, off, 64);
  if ((threadIdx.x & 63) == 0) red[threadIdx.x >> 6] = s;
  __syncthreads();
  if (threadIdx.x == 0) {
    float tot = 0.f;
#pragma unroll
    for (int i = 0; i < 16; i++) tot += red[i];
    out[0] = tot * (1.0f / NROWS);
  }
}

extern "C" void kernel_launch(void* const* d_in, const int* in_sizes, int n_in,
                              void* d_out, int out_size, void* d_ws, size_t ws_size,
                              hipStream_t stream) {
  const float* x = (const float*)d_in[0];
  const int* tg  = (const int*)d_in[1];
  float* out     = (float*)d_out;
  unsigned char* xb = (unsigned char*)d_ws;                    // fp8 X, 4 MiB
  float* partials   = (float*)((char*)d_ws + (4u << 20));      // NT floats

  convert_kernel<<<(NROWS * NDIM / 4) / 256, 256, 0, stream>>>(
      (const float4*)x, (unsigned*)xb);
  loss_kernel<<<NT, 64, 0, stream>>>(xb, tg, partials);
  reduce_kernel<<<1, 1024, 0, stream>>>(partials, out);
}

// Round 7
// 94.702 us; speedup vs baseline: 1.2566x; 1.2566x over previous
//
#include <hip/hip_runtime.h>
#include <hip/hip_bf16.h>
#include <stdint.h>

#define NROWS 8192
#define NDIM  512
#define MARGIN 0.3f
#define NT    2080     // 64*65/2 upper-triangular 128x128 blocks

typedef __attribute__((ext_vector_type(16))) float floatx16;
typedef __attribute__((ext_vector_type(8)))  int   intx8;

// pack 4 floats -> 4 OCP e4m3 bytes (HW cvt, RNE, saturating)
__device__ inline unsigned cvt4_fp8(float4 f) {
  int v = 0;
  v = __builtin_amdgcn_cvt_pk_fp8_f32(f.x, f.y, v, false);
  v = __builtin_amdgcn_cvt_pk_fp8_f32(f.z, f.w, v, true);
  return (unsigned)v;
}

// fp32 -> fp8 e4m3, fully coalesced: lane i reads float4 i, writes u32 i
__global__ void convert_kernel(const float4* __restrict__ in, unsigned* __restrict__ out) {
  int i = blockIdx.x * blockDim.x + threadIdx.x;
  out[i] = cvt4_fp8(in[i]);
}

__device__ inline void gload_lds16(const void* g, void* l) {
  __builtin_amdgcn_global_load_lds(
      (const __attribute__((address_space(1))) unsigned int*)g,
      (__attribute__((address_space(3))) unsigned int*)l, 16, 0, 0);
}

// R22 = R0's proven 128x128 / 3-stage / distance-2 skeleton (42-44us) with
// the tile split across 8 waves of 64x32 instead of 4 waves of 64x64.
// Why: across R0-R6, occupancy never exceeded ~12-17% and every structure
// was latency-bound (MfmaUtil ~12%, HBM <8%, zero bank conflicts). R0's
// per-wave cost was 64 AGPR + ~84 VGPR = ~148 unified regs -> 3 waves/SIMD
// -> 12 waves/CU (3 blocks). Halving the per-wave accumulator (acc[2] = 32
// AGPR) with __launch_bounds__(512,4) caps waves at 128 regs -> 4/SIMD ->
// 16 waves/CU in 2 INDEPENDENT blocks (LDS 2x48KB=96KB fits). MFMA-pipe and
// DMA demand per CU unchanged vs R0; only resident concurrency rises.
// Pipeline per wave: stage ONE 1KB chunk of A and of B per K-step (2 DMA
// loads), steady-state s_waitcnt vmcnt(2) (own stage landed, next stage's 2
// in flight; never 0 until last), raw s_barrier (no lgkm drain: every
// ds_read is consumed by an MFMA before the barrier), stage-after-barrier
// (WAR on the 3rd buffer is barrier-ordered). Swizzle R14-verified.
__launch_bounds__(512, 4)
__global__ void loss_kernel(const unsigned char* __restrict__ Xb, const int* __restrict__ tg,
                            float* __restrict__ partials) {
  __shared__ __align__(16) unsigned char As[3][8192];   // 128 rows x 64 B
  __shared__ __align__(16) unsigned char Bs[3][8192];
  __shared__ float red[8];

  // super-tile decode (8 diagonal supers of 36, then 28 off-diag of 64) —
  // exact R0 decode (99.4us run).
  int t = blockIdx.x;
  int bi, bj;
  if (t < 288) {
    int si = t / 36;
    int q  = t - si * 36;
    int ii = 0;
    while (q >= 8 - ii) { q -= 8 - ii; ii++; }
    bi = si * 8 + ii;
    bj = si * 8 + ii + q;
  } else {
    int q = t - 288;
    int s = q >> 6, r = q & 63;
    int si = 0;
    while (s >= 7 - si) { s -= 7 - si; si++; }
    int sj = si + 1 + s;
    bi = si * 8 + (r >> 3);
    bj = sj * 8 + (r & 7);
  }

  const int tid  = threadIdx.x;
  const int lane = tid & 63;
  const int w    = tid >> 6;             // 0..7
  const int wm   = w >> 2, wn = w & 3;   // 2x4 waves, 64x32 each
  const int g    = lane >> 5;            // MFMA k-group (0/1)
  const int m32  = lane & 31;            // MFMA row/col within 32

  const int rowBase = bi * 128;
  const int colBase = bj * 128;

  // staging: tile = 128 rows x 64 B = 8 chunks of 1 KB (16 rows each);
  // wave w stages chunk w of A and chunk w of B (2 DMA loads/wave/stage).
  // Chunk lane d: row = w*16 + (d>>2), u_phys = d&3; fetches global k-unit
  // u_log = u_phys ^ ((row>>2)&3)  (conflict-free b128 reads, R14-verified;
  // (row>>2)&3 == (srow>>2)&3 since w*16 contributes 0 mod 4).
  const int srow = lane >> 2;
  const int sup  = lane & 3;
  const int ul   = sup ^ ((srow >> 2) & 3);
  const int rloc = w * 16 + srow;
  const unsigned gA = (unsigned)((rowBase + rloc) * NDIM + ul * 16);
  const unsigned gB = (unsigned)((colBase + rloc) * NDIM + ul * 16);

#define STAGE(KT, BUF)                                                    \
  do {                                                                    \
    gload_lds16(Xb + gA + (KT) * 64, &As[BUF][w * 1024]);                 \
    gload_lds16(Xb + gB + (KT) * 64, &Bs[BUF][w * 1024]);                 \
  } while (0)

  floatx16 acc[2];
  acc[0] = (floatx16)(0.f);
  acc[1] = (floatx16)(0.f);

  STAGE(0, 0);
  STAGE(1, 1);

#pragma unroll
  for (int kt = 0; kt < 8; kt++) {
    const int buf = kt % 3;
    // own stage kt landed (2 oldest loads retired); kt+1's 2 stay in flight.
    if (kt < 7) asm volatile("s_waitcnt vmcnt(2)" ::: "memory");
    else        asm volatile("s_waitcnt vmcnt(0)" ::: "memory");
    asm volatile("s_barrier" ::: "memory");        // raw: no lgkm drain
    if (kt < 6) STAGE(kt + 2, (kt + 2) % 3);       // distance-2 prefetch

    // B fragment first (shared across both mt), then A per mt.
    // lane holds k = g*32 + [0,32) of its row as 2 x b128 (u_log = 2g,2g+1),
    // un-swizzled via u_phys = u_log ^ ((row>>2)&3)
    intx8 bf;
    {
      const int row = wn * 32 + m32;
      const int x = (row >> 2) & 3;
      int4 lo = *(const int4*)(&Bs[buf][row * 64 + ((2 * g)     ^ x) * 16]);
      int4 hi = *(const int4*)(&Bs[buf][row * 64 + ((2 * g + 1) ^ x) * 16]);
      intx8 f; f[0]=lo.x; f[1]=lo.y; f[2]=lo.z; f[3]=lo.w;
               f[4]=hi.x; f[5]=hi.y; f[6]=hi.z; f[7]=hi.w;
      bf = f;
    }
#pragma unroll
    for (int mt = 0; mt < 2; mt++) {
      const int row = wm * 64 + mt * 32 + m32;
      const int x = (row >> 2) & 3;
      int4 lo = *(const int4*)(&As[buf][row * 64 + ((2 * g)     ^ x) * 16]);
      int4 hi = *(const int4*)(&As[buf][row * 64 + ((2 * g + 1) ^ x) * 16]);
      intx8 af; af[0]=lo.x; af[1]=lo.y; af[2]=lo.z; af[3]=lo.w;
                af[4]=hi.x; af[5]=hi.y; af[6]=hi.z; af[7]=hi.w;
      acc[mt] = __builtin_amdgcn_mfma_scale_f32_32x32x64_f8f6f4(
          af, bf, acc[mt],
          0 /*A fmt: fp8 e4m3*/, 0 /*B fmt: fp8 e4m3*/,
          0, 127 /*scaleA = 2^0*/, 0, 127 /*scaleB = 2^0*/);
    }
  }

  // Epilogue (R0-verified). 32x32 C/D layout [m74/m101]: col = lane&31,
  // row = (reg&3) + 8*(reg>>2) + 4*(lane>>5), reg in [0,16).
  float lsum = 0.f;
  const bool diag = (bi == bj);
  const int  tc   = tg[colBase + wn * 32 + m32];
  if (!diag) {
#pragma unroll
    for (int mt = 0; mt < 2; mt++) {
#pragma unroll
      for (int q = 0; q < 4; q++) {
        const int4 rlv = *(const int4*)(tg + rowBase + wm * 64 + mt * 32 + 4 * g + 8 * q);
        const int rlab[4] = {rlv.x, rlv.y, rlv.z, rlv.w};
#pragma unroll
        for (int j = 0; j < 4; j++) {
          const float s = acc[mt][q * 4 + j];
          lsum += (rlab[j] == tc) ? ((s < 1.f) ? 1.f - s : 0.f)
                                  : ((s > MARGIN) ? s : 0.f);
        }
      }
    }
    lsum *= 2.f;     // pair weight hoisted
  } else {
    const int col = colBase + wn * 32 + m32;
#pragma unroll
    for (int mt = 0; mt < 2; mt++) {
#pragma unroll
      for (int q = 0; q < 4; q++) {
        const int rbase = wm * 64 + mt * 32 + 4 * g + 8 * q;
        const int4 rlv = *(const int4*)(tg + rowBase + rbase);
        const int rlab[4] = {rlv.x, rlv.y, rlv.z, rlv.w};
#pragma unroll
        for (int j = 0; j < 4; j++) {
          const float s = acc[mt][q * 4 + j];
          float c = (rlab[j] == tc) ? ((s < 1.f) ? 1.f - s : 0.f)
                                    : ((s > MARGIN) ? s : 0.f);
          const int row = rowBase + rbase + j;
          float wgt = (row < col) ? 2.f : ((row == col) ? 1.f : 0.f);
          lsum += wgt * c;
        }
      }
    }
  }

  // block reduce, ONE non-atomic partial store per block
#pragma unroll
  for (int off = 32; off > 0; off >>= 1) lsum += __shfl_down(lsum, off, 64);
  if (lane == 0) red[w] = lsum;
  __syncthreads();
  if (tid == 0) {
    float s = 0.f;
#pragma unroll
    for (int i = 0; i < 8; i++) s += red[i];
    partials[blockIdx.x] = s;
  }
#undef STAGE
}

// NT partials -> scalar; one 256-thread block
__global__ void reduce_kernel(const float* __restrict__ partials, float* __restrict__ out) {
  __shared__ float red[4];
  float s = 0.f;
  for (int i = threadIdx.x; i < NT; i += 256) s += partials[i];
#pragma unroll
  for (int off = 32; off > 0; off >>= 1) s += __shfl_down(s, off, 64);
  if ((threadIdx.x & 63) == 0) red[threadIdx.x >> 6] = s;
  __syncthreads();
  if (threadIdx.x == 0)
    out[0] = (red[0] + red[1] + red[2] + red[3]) * (1.0f / NROWS);
}

extern "C" void kernel_launch(void* const* d_in, const int* in_sizes, int n_in,
                              void* d_out, int out_size, void* d_ws, size_t ws_size,
                              hipStream_t stream) {
  const float* x = (const float*)d_in[0];
  const int* tg  = (const int*)d_in[1];
  float* out     = (float*)d_out;
  unsigned char* xb = (unsigned char*)d_ws;                    // fp8 X, 4 MiB
  float* partials   = (float*)((char*)d_ws + (4u << 20));      // NT floats

  convert_kernel<<<(NROWS * NDIM / 4) / 256, 256, 0, stream>>>(
      (const float4*)x, (unsigned*)xb);
  loss_kernel<<<NT, 512, 0, stream>>>(xb, tg, partials);
  reduce_kernel<<<1, 256, 0, stream>>>(partials, out);
}